// Round 7
// baseline (184.432 us; speedup 1.0000x reference)
//
#include <hip/hip_runtime.h>

#define D_DIM 128
#define DE_DIM 64
#define LN_EPS 1e-5f
#define LEAKY 0.2f

typedef __attribute__((ext_vector_type(4))) float f32x4;
typedef __attribute__((ext_vector_type(8))) short s16x8;

static __device__ __forceinline__ unsigned short f2bf(float f) {
  unsigned int u = __float_as_uint(f);
  unsigned int r = (u + 0x7fffu + ((u >> 16) & 1u)) >> 16;
  return (unsigned short)r;
}

// ---------- CSR build: histogram -> hierarchical scan ----------

__global__ void hist_kernel(const int* __restrict__ dst, int* __restrict__ cnt, int E) {
  int e = blockIdx.x * blockDim.x + threadIdx.x;
  if (e < E) atomicAdd(&cnt[dst[e]], 1);
}

__global__ __launch_bounds__(256) void scan1_kernel(
    const int* __restrict__ cnt, int* __restrict__ bsum, int N)
{
  __shared__ int red[256];
  int b = blockIdx.x, tid = threadIdx.x;
  int i0 = b * 1024 + tid * 4;
  int s = 0;
  if (i0 + 3 < N) {
    int4 v = *reinterpret_cast<const int4*>(&cnt[i0]);
    s = v.x + v.y + v.z + v.w;
  } else {
#pragma unroll
    for (int j = 0; j < 4; ++j) if (i0 + j < N) s += cnt[i0 + j];
  }
  red[tid] = s;
  __syncthreads();
  for (int off = 128; off; off >>= 1) {
    if (tid < off) red[tid] += red[tid + off];
    __syncthreads();
  }
  if (tid == 0) bsum[b] = red[0];
}

__global__ void scan2_kernel(const int* __restrict__ bsum, int* __restrict__ boff,
                             int* __restrict__ row_ptrN, int nb)
{
  int l = threadIdx.x;   // 64 threads
  int v = (l < nb) ? bsum[l] : 0;
  int inc = v;
#pragma unroll
  for (int off = 1; off < 64; off <<= 1) {
    int t = __shfl_up(inc, off);
    if (l >= off) inc += t;
  }
  if (l < nb) boff[l] = inc - v;
  if (l == 63) *row_ptrN = inc;
}

__global__ __launch_bounds__(256) void scan3_kernel(
    const int* __restrict__ cnt, const int* __restrict__ boff,
    int* __restrict__ row_ptr, int* __restrict__ cursor, int N)
{
  __shared__ int wsum[4];
  int b = blockIdx.x, tid = threadIdx.x;
  int lane = tid & 63, wv = tid >> 6;
  int i0 = b * 1024 + tid * 4;
  int c[4];
  int s = 0;
#pragma unroll
  for (int j = 0; j < 4; ++j) {
    int i = i0 + j;
    c[j] = (i < N) ? cnt[i] : 0;
    s += c[j];
  }
  int inc = s;
#pragma unroll
  for (int off = 1; off < 64; off <<= 1) {
    int t = __shfl_up(inc, off);
    if (lane >= off) inc += t;
  }
  if (lane == 63) wsum[wv] = inc;
  __syncthreads();
  int woff = 0;
  for (int w = 0; w < wv; ++w) woff += wsum[w];
  int excl = boff[b] + woff + (inc - s);
#pragma unroll
  for (int j = 0; j < 4; ++j) {
    int i = i0 + j;
    if (i < N) { row_ptr[i] = excl; cursor[i] = excl; excl += c[j]; }
  }
}

// ---------- merged weight pre-pack ----------
__global__ __launch_bounds__(256) void prep_weights_kernel(
    const float* __restrict__ W_rel, const float* __restrict__ W_w,
    unsigned short* __restrict__ wrel_pk, unsigned short* __restrict__ ww_pk)
{
  int tid = blockIdx.x * blockDim.x + threadIdx.x;   // 73728 total
  if (tid < 8192) {
    int j = tid & 7, lane = (tid >> 3) & 63, ks = (tid >> 9) & 1, dg = tid >> 10;
    int k = ks * 32 + 8 * (lane >> 4) + j;
    int col = 16 * dg + (lane & 15);
    wrel_pk[tid] = f2bf(W_rel[k * D_DIM + col]);
  } else {
    int t2 = tid - 8192;
    if (t2 < 65536) {
      int j = t2 & 7, lane = (t2 >> 3) & 63, dg = (t2 >> 9) & 7, kc = t2 >> 12;
      int c = kc * 32 + 8 * (lane >> 4) + j;
      int d = 16 * dg + (lane & 15);
      ww_pk[t2] = f2bf(W_w[(long long)(c & 127) * 512 + (c >> 7) * 128 + d]);
    }
  }
}

// ---------- node attention partials ----------
__global__ __launch_bounds__(256) void node_att_kernel(
    const float* __restrict__ h, const float* __restrict__ W_att,
    float* __restrict__ a12, int N)
{
  int lane = threadIdx.x & 63;
  int wid = (int)((blockIdx.x * (long long)blockDim.x + threadIdx.x) >> 6);
  if (wid >= N) return;
  const float* hr = &h[(long long)wid * D_DIM];
  float h0 = hr[lane], h1 = hr[64 + lane];
  float p[8];
#pragma unroll
  for (int hd = 0; hd < 4; ++hd) {
    p[hd]     = h0 * W_att[lane * 4 + hd]         + h1 * W_att[(64 + lane) * 4 + hd];
    p[4 + hd] = h0 * W_att[(128 + lane) * 4 + hd] + h1 * W_att[(192 + lane) * 4 + hd];
  }
#pragma unroll
  for (int j = 0; j < 8; ++j) {
    float v = p[j];
#pragma unroll
    for (int off = 32; off; off >>= 1) v += __shfl_xor(v, off);
    if (lane == 0) a12[(long long)wid * 8 + j] = v;
  }
}

// ---------- fused edge pass, transposed MFMA, 64 edges/wave, 2-deep pipelined loads ----------
#define LOADT(buf, t) do {                                                       \
    long long er_ = wbase + (t) * 16 + cq;                                       \
    const float* efp_ = &edge_feat[er_ * DE_DIM + 8 * G];                        \
    if (er_ < E) {                                                               \
      r[buf][0] = *reinterpret_cast<const float4*>(&efp_[0]);                    \
      r[buf][1] = *reinterpret_cast<const float4*>(&efp_[4]);                    \
      r[buf][2] = *reinterpret_cast<const float4*>(&efp_[32]);                   \
      r[buf][3] = *reinterpret_cast<const float4*>(&efp_[36]);                   \
    } else {                                                                     \
      r[buf][0] = r[buf][1] = r[buf][2] = r[buf][3] = fz4;                       \
    }                                                                            \
  } while (0)

__global__ __launch_bounds__(256, 4) void edge_mfma_kernel(
    const float* __restrict__ edge_feat,
    const unsigned short* __restrict__ wrel_pk, const float* __restrict__ b_rel,
    const float* __restrict__ ln_g, const float* __restrict__ ln_b,
    const float* __restrict__ W_att,
    float* __restrict__ u_part, int E)
{
  __shared__ unsigned short Wlds[8192];   // 16 KB: full W_rel fragment pack
  {
    int tid = threadIdx.x;
    const uint4* sp = reinterpret_cast<const uint4*>(wrel_pk);
    uint4* dp = reinterpret_cast<uint4*>(Wlds);
#pragma unroll
    for (int i = 0; i < 4; ++i) dp[tid + 256 * i] = sp[tid + 256 * i];
  }
  __syncthreads();

  int l = threadIdx.x & 63;
  int wv = threadIdx.x >> 6;
  long long wbase = (long long)blockIdx.x * 256 + wv * 64;
  int G = l >> 4, cq = l & 15;
  float4 fz4 = make_float4(0.f, 0.f, 0.f, 0.f);
  f32x4 zero4 = {0.f, 0.f, 0.f, 0.f};

  float4 r[2][4];
  LOADT(0, 0);

#pragma unroll
  for (int t = 0; t < 4; ++t) {
    int cur = t & 1, nxt = cur ^ 1;
    if (t < 3) LOADT(nxt, t + 1);     // issue next tile's HBM loads early

    s16x8 ef0, ef1;
    {
      const float* q0 = &r[cur][0].x;
      const float* q1 = &r[cur][1].x;
      const float* q2 = &r[cur][2].x;
      const float* q3 = &r[cur][3].x;
#pragma unroll
      for (int j = 0; j < 4; ++j) {
        ef0[j]     = (short)f2bf(q0[j]);
        ef0[4 + j] = (short)f2bf(q1[j]);
        ef1[j]     = (short)f2bf(q2[j]);
        ef1[4 + j] = (short)f2bf(q3[j]);
      }
    }

    f32x4 acc[8];
#pragma unroll
    for (int dg = 0; dg < 8; ++dg) acc[dg] = zero4;
#pragma unroll
    for (int dg = 0; dg < 8; ++dg) {
      s16x8 w0 = *reinterpret_cast<const s16x8*>(&Wlds[((dg * 2 + 0) * 64 + l) * 8]);
      s16x8 w1 = *reinterpret_cast<const s16x8*>(&Wlds[((dg * 2 + 1) * 64 + l) * 8]);
      acc[dg] = __builtin_amdgcn_mfma_f32_16x16x32_bf16(w0, ef0, acc[dg], 0, 0, 0);
      acc[dg] = __builtin_amdgcn_mfma_f32_16x16x32_bf16(w1, ef1, acc[dg], 0, 0, 0);
    }

    // lane owns one edge (col cq), d = 16*dg + 4*G + i
    float s = 0.f, q = 0.f;
#pragma unroll
    for (int dg = 0; dg < 8; ++dg) {
      float4 br = *reinterpret_cast<const float4*>(&b_rel[16 * dg + 4 * G]);
      const float* brp = &br.x;
#pragma unroll
      for (int i = 0; i < 4; ++i) {
        float v = acc[dg][i] + brp[i];
        acc[dg][i] = v;
        s += v; q += v * v;
      }
    }
    s += __shfl_xor(s, 16); s += __shfl_xor(s, 32);
    q += __shfl_xor(q, 16); q += __shfl_xor(q, 32);
    float mu = s * (1.f / 128.f);
    float var = q * (1.f / 128.f) - mu * mu;
    float rstd = rsqrtf(var + LN_EPS);

    float u0 = 0.f, u1 = 0.f, u2 = 0.f, u3 = 0.f;
#pragma unroll
    for (int dg = 0; dg < 8; ++dg) {
      int d0 = 16 * dg + 4 * G;
      float4 g  = *reinterpret_cast<const float4*>(&ln_g[d0]);
      float4 bb = *reinterpret_cast<const float4*>(&ln_b[d0]);
      const float* gp = &g.x; const float* bp = &bb.x;
#pragma unroll
      for (int i = 0; i < 4; ++i) {
        float w = (acc[dg][i] - mu) * rstd * gp[i] + bp[i];
        w = fmaxf(w, 0.f);
        float4 wa = *reinterpret_cast<const float4*>(&W_att[(256 + d0 + i) * 4]);
        u0 = fmaf(w, wa.x, u0);
        u1 = fmaf(w, wa.y, u1);
        u2 = fmaf(w, wa.z, u2);
        u3 = fmaf(w, wa.w, u3);
      }
    }
    u0 += __shfl_xor(u0, 16); u0 += __shfl_xor(u0, 32);
    u1 += __shfl_xor(u1, 16); u1 += __shfl_xor(u1, 32);
    u2 += __shfl_xor(u2, 16); u2 += __shfl_xor(u2, 32);
    u3 += __shfl_xor(u3, 16); u3 += __shfl_xor(u3, 32);

    if (l < 16) {
      long long e = wbase + t * 16 + l;
      if (e < E) {
        float4 o = make_float4(u0, u1, u2, u3);
        *reinterpret_cast<float4*>(&u_part[e * 4]) = o;
      }
    }
  }
}

// ---------- fused scatter + per-edge logit (thread-per-edge) ----------
__global__ __launch_bounds__(256) void scatter_logit_kernel(
    const int* __restrict__ src, const int* __restrict__ dst, int* __restrict__ cursor,
    const float* __restrict__ u_part, const float* __restrict__ a12,
    const float* __restrict__ b_att,
    int* __restrict__ src_sorted, float* __restrict__ u_sorted, int E)
{
  int e = blockIdx.x * blockDim.x + threadIdx.x;
  if (e >= E) return;
  int dN = dst[e], sN = src[e];
  int p = atomicAdd(&cursor[dN], 1);
  src_sorted[p] = sN;
  float4 up = *reinterpret_cast<const float4*>(&u_part[(long long)e * 4]);
  float4 a1 = *reinterpret_cast<const float4*>(&a12[(long long)dN * 8]);
  float4 a2 = *reinterpret_cast<const float4*>(&a12[(long long)sN * 8 + 4]);
  float4 ba = *reinterpret_cast<const float4*>(&b_att[0]);
  float4 o;
  o.x = a1.x + a2.x + up.x + ba.x; o.x = (o.x >= 0.f) ? o.x : LEAKY * o.x;
  o.y = a1.y + a2.y + up.y + ba.y; o.y = (o.y >= 0.f) ? o.y : LEAKY * o.y;
  o.z = a1.z + a2.z + up.z + ba.z; o.z = (o.z >= 0.f) ? o.z : LEAKY * o.z;
  o.w = a1.w + a2.w + up.w + ba.w; o.w = (o.w >= 0.f) ? o.w : LEAKY * o.w;
  *reinterpret_cast<float4*>(&u_sorted[(long long)p * 4]) = o;
}

// ---------- online segment softmax + gather aggregate (wave per node, 1-deep pipeline) ----------
__global__ __launch_bounds__(256) void node_agg_kernel(
    const float* __restrict__ h, const int* __restrict__ src_sorted,
    const float* __restrict__ u_sorted, const int* __restrict__ row_ptr,
    unsigned short* __restrict__ t, int N)
{
  int lane = threadIdx.x & 63;
  int n = (int)((blockIdx.x * (long long)blockDim.x + threadIdx.x) >> 6);
  if (n >= N) return;
  int lo = row_ptr[n], hi = row_ptr[n + 1];
  unsigned short* tb = &t[(long long)n * 512];
  if (lo == hi) {
#pragma unroll
    for (int hd = 0; hd < 4; ++hd) {
      tb[hd * 128 + lane] = 0;
      tb[hd * 128 + 64 + lane] = 0;
    }
    return;
  }
  float m0 = -1e30f, m1 = -1e30f, m2 = -1e30f, m3 = -1e30f;
  float d0 = 0.f, d1 = 0.f, d2 = 0.f, d3 = 0.f;
  float acc[8];
#pragma unroll
  for (int i = 0; i < 8; ++i) acc[i] = 0.f;

  // prime pipeline
  int sN = src_sorted[lo];
  float4 u = *reinterpret_cast<const float4*>(&u_sorted[(long long)lo * 4]);
  const float* hs = &h[(long long)sN * D_DIM];
  float h0 = hs[lane], h1 = hs[64 + lane];

  for (int p = lo; p < hi; ++p) {
    float4 uc = u;
    float h0c = h0, h1c = h1;
    if (p + 1 < hi) {             // prefetch next edge while computing current
      int sn2 = src_sorted[p + 1];
      u = *reinterpret_cast<const float4*>(&u_sorted[(long long)(p + 1) * 4]);
      const float* hs2 = &h[(long long)sn2 * D_DIM];
      h0 = hs2[lane]; h1 = hs2[64 + lane];
    }
    float nm0 = fmaxf(m0, uc.x), nm1 = fmaxf(m1, uc.y);
    float nm2 = fmaxf(m2, uc.z), nm3 = fmaxf(m3, uc.w);
    float s0 = __expf(m0 - nm0), s1 = __expf(m1 - nm1);
    float s2 = __expf(m2 - nm2), s3 = __expf(m3 - nm3);
    float p0 = __expf(uc.x - nm0), p1 = __expf(uc.y - nm1);
    float p2 = __expf(uc.z - nm2), p3 = __expf(uc.w - nm3);
    m0 = nm0; m1 = nm1; m2 = nm2; m3 = nm3;
    d0 = fmaf(d0, s0, p0); d1 = fmaf(d1, s1, p1);
    d2 = fmaf(d2, s2, p2); d3 = fmaf(d3, s3, p3);
    acc[0] = fmaf(acc[0], s0, p0 * h0c); acc[1] = fmaf(acc[1], s0, p0 * h1c);
    acc[2] = fmaf(acc[2], s1, p1 * h0c); acc[3] = fmaf(acc[3], s1, p1 * h1c);
    acc[4] = fmaf(acc[4], s2, p2 * h0c); acc[5] = fmaf(acc[5], s2, p2 * h1c);
    acc[6] = fmaf(acc[6], s3, p3 * h0c); acc[7] = fmaf(acc[7], s3, p3 * h1c);
  }
  float r0 = 1.f / d0, r1 = 1.f / d1, r2 = 1.f / d2, r3 = 1.f / d3;
  tb[0 * 128 + lane] = f2bf(acc[0] * r0); tb[0 * 128 + 64 + lane] = f2bf(acc[1] * r0);
  tb[1 * 128 + lane] = f2bf(acc[2] * r1); tb[1 * 128 + 64 + lane] = f2bf(acc[3] * r1);
  tb[2 * 128 + lane] = f2bf(acc[4] * r2); tb[2 * 128 + 64 + lane] = f2bf(acc[5] * r2);
  tb[3 * 128 + lane] = f2bf(acc[6] * r3); tb[3 * 128 + 64 + lane] = f2bf(acc[7] * r3);
}

// ---------- final node GEMM via MFMA ----------
__global__ __launch_bounds__(256) void node_final_mfma(
    const unsigned short* __restrict__ t_bf, const unsigned short* __restrict__ ww_pk,
    const float* __restrict__ b_w, const int* __restrict__ row_ptr,
    const float* __restrict__ h, const float* __restrict__ prelu_a,
    float* __restrict__ out, int N)
{
  int l = threadIdx.x & 63;
  int wv = threadIdx.x >> 6;
  int base = blockIdx.x * 128 + wv * 32;

  f32x4 zero4 = {0.f, 0.f, 0.f, 0.f};
  f32x4 acc[2][8];
#pragma unroll
  for (int rg = 0; rg < 2; ++rg)
#pragma unroll
    for (int dg = 0; dg < 8; ++dg) acc[rg][dg] = zero4;

  s16x8 azero;
#pragma unroll
  for (int j = 0; j < 8; ++j) azero[j] = 0;

  for (int kc = 0; kc < 16; ++kc) {
    s16x8 a[2];
#pragma unroll
    for (int rg = 0; rg < 2; ++rg) {
      int row = base + rg * 16 + (l & 15);
      a[rg] = (row < N)
        ? *reinterpret_cast<const s16x8*>(&t_bf[(long long)row * 512 + kc * 32 + 8 * (l >> 4)])
        : azero;
    }
#pragma unroll
    for (int dg = 0; dg < 8; ++dg) {
      s16x8 b = *reinterpret_cast<const s16x8*>(&ww_pk[((long long)(kc * 8 + dg) * 64 + l) * 8]);
      acc[0][dg] = __builtin_amdgcn_mfma_f32_16x16x32_bf16(a[0], b, acc[0][dg], 0, 0, 0);
      acc[1][dg] = __builtin_amdgcn_mfma_f32_16x16x32_bf16(a[1], b, acc[1][dg], 0, 0, 0);
    }
  }

  float pa = prelu_a[0];
  int cq = l & 15;
  float bs[8];
#pragma unroll
  for (int dg = 0; dg < 8; ++dg) {
    int col = 16 * dg + cq;
    bs[dg] = b_w[col] + b_w[128 + col] + b_w[256 + col] + b_w[384 + col];
  }
#pragma unroll
  for (int rg = 0; rg < 2; ++rg)
#pragma unroll
    for (int i = 0; i < 4; ++i) {
      int row = base + rg * 16 + 4 * (l >> 4) + i;
      if (row >= N) continue;
      bool has = row_ptr[row + 1] > row_ptr[row];
#pragma unroll
      for (int dg = 0; dg < 8; ++dg) {
        int col = 16 * dg + cq;
        float v = (acc[rg][dg][i] + bs[dg]) * 0.25f;
        v = (v >= 0.f) ? v : pa * v;
        if (!has) v = h[(long long)row * 128 + col];
        out[(long long)row * 128 + col] = v;
      }
    }
}

extern "C" void kernel_launch(void* const* d_in, const int* in_sizes, int n_in,
                              void* d_out, int out_size, void* d_ws, size_t ws_size,
                              hipStream_t stream)
{
  const float* h         = (const float*)d_in[0];
  const float* edge_feat = (const float*)d_in[1];
  const int*   src       = (const int*)d_in[2];
  const int*   dst       = (const int*)d_in[3];
  const float* W_rel     = (const float*)d_in[4];
  const float* b_rel     = (const float*)d_in[5];
  const float* ln_g      = (const float*)d_in[6];
  const float* ln_b      = (const float*)d_in[7];
  const float* W_att     = (const float*)d_in[8];
  const float* b_att     = (const float*)d_in[9];
  const float* W_w       = (const float*)d_in[10];
  const float* b_w       = (const float*)d_in[11];
  const float* prelu_a   = (const float*)d_in[12];

  int N = in_sizes[0] / D_DIM;
  int E = in_sizes[2];
  int nb = (N + 1023) / 1024;

  char* ws = (char*)d_ws;
  size_t off = 0;
  unsigned short* t_bf    = (unsigned short*)(ws + off); off += (size_t)N * 512 * 2;
  float* u_part           = (float*)(ws + off);          off += (size_t)E * 4 * 4;
  float* u_sorted         = (float*)(ws + off);          off += (size_t)E * 4 * 4;
  float* a12              = (float*)(ws + off);          off += (size_t)N * 8 * 4;
  int*   row_ptr          = (int*)(ws + off);            off += (size_t)(N + 1) * 4;
  int*   cnt              = (int*)(ws + off);            off += (size_t)N * 4;
  int*   cursor           = (int*)(ws + off);            off += (size_t)N * 4;
  int*   src_sorted       = (int*)(ws + off);            off += (size_t)E * 4;
  unsigned short* wrel_pk = (unsigned short*)(ws + off); off += 8192 * 2;
  unsigned short* ww_pk   = (unsigned short*)(ws + off); off += 65536 * 2;
  int*   bsum             = (int*)(ws + off);            off += 64 * 4;
  int*   boff             = (int*)(ws + off);            off += 64 * 4;

  hipMemsetAsync(cnt, 0, (size_t)N * 4, stream);
  hist_kernel<<<(E + 255) / 256, 256, 0, stream>>>(dst, cnt, E);
  scan1_kernel<<<nb, 256, 0, stream>>>(cnt, bsum, N);
  scan2_kernel<<<1, 64, 0, stream>>>(bsum, boff, &row_ptr[N], nb);
  scan3_kernel<<<nb, 256, 0, stream>>>(cnt, boff, row_ptr, cursor, N);
  prep_weights_kernel<<<288, 256, 0, stream>>>(W_rel, W_w, wrel_pk, ww_pk);
  node_att_kernel<<<(N * 64 + 255) / 256, 256, 0, stream>>>(h, W_att, a12, N);
  edge_mfma_kernel<<<(E + 255) / 256, 256, 0, stream>>>(edge_feat, wrel_pk, b_rel,
                                                        ln_g, ln_b, W_att, u_part, E);
  scatter_logit_kernel<<<(E + 255) / 256, 256, 0, stream>>>(src, dst, cursor, u_part, a12,
                                                            b_att, src_sorted, u_sorted, E);
  node_agg_kernel<<<(int)(((long long)N * 64 + 255) / 256), 256, 0, stream>>>(
      h, src_sorted, u_sorted, row_ptr, t_bf, N);
  node_final_mfma<<<(N + 127) / 128, 256, 0, stream>>>(t_bf, ww_pk, b_w, row_ptr, h, prelu_a,
                                                       (float*)d_out, N);
}

// Round 8
// 161.067 us; speedup vs baseline: 1.1451x; 1.1451x over previous
//
#include <hip/hip_runtime.h>

#define D_DIM 128
#define DE_DIM 64
#define LN_EPS 1e-5f
#define LEAKY 0.2f

typedef __attribute__((ext_vector_type(4))) float f32x4;
typedef __attribute__((ext_vector_type(8))) short s16x8;

static __device__ __forceinline__ unsigned short f2bf(float f) {
  unsigned int u = __float_as_uint(f);
  unsigned int r = (u + 0x7fffu + ((u >> 16) & 1u)) >> 16;
  return (unsigned short)r;
}

// ---------- CSR build: histogram -> hierarchical scan ----------

__global__ void hist_kernel(const int* __restrict__ dst, int* __restrict__ cnt, int E) {
  int e = blockIdx.x * blockDim.x + threadIdx.x;
  if (e < E) atomicAdd(&cnt[dst[e]], 1);
}

__global__ __launch_bounds__(256) void scan1_kernel(
    const int* __restrict__ cnt, int* __restrict__ bsum, int N)
{
  __shared__ int red[256];
  int b = blockIdx.x, tid = threadIdx.x;
  int i0 = b * 1024 + tid * 4;
  int s = 0;
  if (i0 + 3 < N) {
    int4 v = *reinterpret_cast<const int4*>(&cnt[i0]);
    s = v.x + v.y + v.z + v.w;
  } else {
#pragma unroll
    for (int j = 0; j < 4; ++j) if (i0 + j < N) s += cnt[i0 + j];
  }
  red[tid] = s;
  __syncthreads();
  for (int off = 128; off; off >>= 1) {
    if (tid < off) red[tid] += red[tid + off];
    __syncthreads();
  }
  if (tid == 0) bsum[b] = red[0];
}

__global__ void scan2_kernel(const int* __restrict__ bsum, int* __restrict__ boff,
                             int* __restrict__ row_ptrN, int nb)
{
  int l = threadIdx.x;   // 64 threads
  int v = (l < nb) ? bsum[l] : 0;
  int inc = v;
#pragma unroll
  for (int off = 1; off < 64; off <<= 1) {
    int t = __shfl_up(inc, off);
    if (l >= off) inc += t;
  }
  if (l < nb) boff[l] = inc - v;
  if (l == 63) *row_ptrN = inc;
}

__global__ __launch_bounds__(256) void scan3_kernel(
    const int* __restrict__ cnt, const int* __restrict__ boff,
    int* __restrict__ row_ptr, int* __restrict__ cursor, int N)
{
  __shared__ int wsum[4];
  int b = blockIdx.x, tid = threadIdx.x;
  int lane = tid & 63, wv = tid >> 6;
  int i0 = b * 1024 + tid * 4;
  int c[4];
  int s = 0;
#pragma unroll
  for (int j = 0; j < 4; ++j) {
    int i = i0 + j;
    c[j] = (i < N) ? cnt[i] : 0;
    s += c[j];
  }
  int inc = s;
#pragma unroll
  for (int off = 1; off < 64; off <<= 1) {
    int t = __shfl_up(inc, off);
    if (lane >= off) inc += t;
  }
  if (lane == 63) wsum[wv] = inc;
  __syncthreads();
  int woff = 0;
  for (int w = 0; w < wv; ++w) woff += wsum[w];
  int excl = boff[b] + woff + (inc - s);
#pragma unroll
  for (int j = 0; j < 4; ++j) {
    int i = i0 + j;
    if (i < N) { row_ptr[i] = excl; cursor[i] = excl; excl += c[j]; }
  }
}

// ---------- merged weight pre-pack ----------
__global__ __launch_bounds__(256) void prep_weights_kernel(
    const float* __restrict__ W_rel, const float* __restrict__ W_w,
    unsigned short* __restrict__ wrel_pk, unsigned short* __restrict__ ww_pk)
{
  int tid = blockIdx.x * blockDim.x + threadIdx.x;   // 73728 total
  if (tid < 8192) {
    int j = tid & 7, lane = (tid >> 3) & 63, ks = (tid >> 9) & 1, dg = tid >> 10;
    int k = ks * 32 + 8 * (lane >> 4) + j;
    int col = 16 * dg + (lane & 15);
    wrel_pk[tid] = f2bf(W_rel[k * D_DIM + col]);
  } else {
    int t2 = tid - 8192;
    if (t2 < 65536) {
      int j = t2 & 7, lane = (t2 >> 3) & 63, dg = (t2 >> 9) & 7, kc = t2 >> 12;
      int c = kc * 32 + 8 * (lane >> 4) + j;
      int d = 16 * dg + (lane & 15);
      ww_pk[t2] = f2bf(W_w[(long long)(c & 127) * 512 + (c >> 7) * 128 + d]);
    }
  }
}

// ---------- node attention partials ----------
__global__ __launch_bounds__(256) void node_att_kernel(
    const float* __restrict__ h, const float* __restrict__ W_att,
    float* __restrict__ a12, int N)
{
  int lane = threadIdx.x & 63;
  int wid = (int)((blockIdx.x * (long long)blockDim.x + threadIdx.x) >> 6);
  if (wid >= N) return;
  const float* hr = &h[(long long)wid * D_DIM];
  float h0 = hr[lane], h1 = hr[64 + lane];
  float p[8];
#pragma unroll
  for (int hd = 0; hd < 4; ++hd) {
    p[hd]     = h0 * W_att[lane * 4 + hd]         + h1 * W_att[(64 + lane) * 4 + hd];
    p[4 + hd] = h0 * W_att[(128 + lane) * 4 + hd] + h1 * W_att[(192 + lane) * 4 + hd];
  }
#pragma unroll
  for (int j = 0; j < 8; ++j) {
    float v = p[j];
#pragma unroll
    for (int off = 32; off; off >>= 1) v += __shfl_xor(v, off);
    if (lane == 0) a12[(long long)wid * 8 + j] = v;
  }
}

// ---------- fused edge pass, transposed MFMA: x^T = W_rel^T @ ef^T ----------
// (R6 version: 16 edges/wave, no reg double-buffer -> no spill; VGPR 72, WRITE=u_part only)
__global__ __launch_bounds__(256, 4) void edge_mfma_kernel(
    const float* __restrict__ edge_feat,
    const unsigned short* __restrict__ wrel_pk, const float* __restrict__ b_rel,
    const float* __restrict__ ln_g, const float* __restrict__ ln_b,
    const float* __restrict__ W_att,
    float* __restrict__ u_part, int E)
{
  __shared__ unsigned short Wlds[8192];   // 16 KB: full W_rel fragment pack
  {
    int tid = threadIdx.x;
    const uint4* sp = reinterpret_cast<const uint4*>(wrel_pk);
    uint4* dp = reinterpret_cast<uint4*>(Wlds);
#pragma unroll
    for (int i = 0; i < 4; ++i) dp[tid + 256 * i] = sp[tid + 256 * i];
  }
  __syncthreads();

  int l = threadIdx.x & 63;
  int wv = threadIdx.x >> 6;
  long long e0 = (long long)blockIdx.x * 64 + wv * 16;

  // B fragment = ef^T: lane holds edge (l&15), k = 8*(l>>4)+j (+32*ks)
  long long er = e0 + (l & 15);
  const float* ef = &edge_feat[er * DE_DIM + 8 * (l >> 4)];
  bool erok = (er < E);
  s16x8 efrag[2];
#pragma unroll
  for (int ks = 0; ks < 2; ++ks) {
    s16x8 a;
    if (erok) {
      float4 v0 = *reinterpret_cast<const float4*>(&ef[ks * 32]);
      float4 v1 = *reinterpret_cast<const float4*>(&ef[ks * 32 + 4]);
      a[0] = (short)f2bf(v0.x); a[1] = (short)f2bf(v0.y);
      a[2] = (short)f2bf(v0.z); a[3] = (short)f2bf(v0.w);
      a[4] = (short)f2bf(v1.x); a[5] = (short)f2bf(v1.y);
      a[6] = (short)f2bf(v1.z); a[7] = (short)f2bf(v1.w);
    } else {
#pragma unroll
      for (int j = 0; j < 8; ++j) a[j] = 0;
    }
    efrag[ks] = a;
  }

  f32x4 zero4 = {0.f, 0.f, 0.f, 0.f};
  f32x4 acc[8];
#pragma unroll
  for (int dg = 0; dg < 8; ++dg) acc[dg] = zero4;

#pragma unroll
  for (int dg = 0; dg < 8; ++dg) {
    s16x8 w0 = *reinterpret_cast<const s16x8*>(&Wlds[((dg * 2 + 0) * 64 + l) * 8]);
    s16x8 w1 = *reinterpret_cast<const s16x8*>(&Wlds[((dg * 2 + 1) * 64 + l) * 8]);
    acc[dg] = __builtin_amdgcn_mfma_f32_16x16x32_bf16(w0, efrag[0], acc[dg], 0, 0, 0);
    acc[dg] = __builtin_amdgcn_mfma_f32_16x16x32_bf16(w1, efrag[1], acc[dg], 0, 0, 0);
  }

  // lane's d-values: d = 16*dg + 4*(l>>4) + i  (32 per lane, one edge per lane)
  int G = l >> 4;
  float s = 0.f, q = 0.f;
#pragma unroll
  for (int dg = 0; dg < 8; ++dg) {
    float4 br = *reinterpret_cast<const float4*>(&b_rel[16 * dg + 4 * G]);
    const float* brp = &br.x;
#pragma unroll
    for (int i = 0; i < 4; ++i) {
      float v = acc[dg][i] + brp[i];
      acc[dg][i] = v;
      s += v; q += v * v;
    }
  }
  s += __shfl_xor(s, 16); s += __shfl_xor(s, 32);
  q += __shfl_xor(q, 16); q += __shfl_xor(q, 32);
  float mu = s * (1.f / 128.f);
  float var = q * (1.f / 128.f) - mu * mu;
  float rstd = rsqrtf(var + LN_EPS);

  float u0 = 0.f, u1 = 0.f, u2 = 0.f, u3 = 0.f;
#pragma unroll
  for (int dg = 0; dg < 8; ++dg) {
    int d0 = 16 * dg + 4 * G;
    float4 g  = *reinterpret_cast<const float4*>(&ln_g[d0]);
    float4 bb = *reinterpret_cast<const float4*>(&ln_b[d0]);
    const float* gp = &g.x; const float* bp = &bb.x;
#pragma unroll
    for (int i = 0; i < 4; ++i) {
      float w = (acc[dg][i] - mu) * rstd * gp[i] + bp[i];
      w = fmaxf(w, 0.f);
      float4 wa = *reinterpret_cast<const float4*>(&W_att[(256 + d0 + i) * 4]);
      u0 = fmaf(w, wa.x, u0);
      u1 = fmaf(w, wa.y, u1);
      u2 = fmaf(w, wa.z, u2);
      u3 = fmaf(w, wa.w, u3);
    }
  }
  u0 += __shfl_xor(u0, 16); u0 += __shfl_xor(u0, 32);
  u1 += __shfl_xor(u1, 16); u1 += __shfl_xor(u1, 32);
  u2 += __shfl_xor(u2, 16); u2 += __shfl_xor(u2, 32);
  u3 += __shfl_xor(u3, 16); u3 += __shfl_xor(u3, 32);

  if (l < 16 && erok) {
    float4 o = make_float4(u0, u1, u2, u3);
    *reinterpret_cast<float4*>(&u_part[er * 4]) = o;
  }
}

// ---------- fused scatter + per-edge logit (thread-per-edge) ----------
__global__ __launch_bounds__(256) void scatter_logit_kernel(
    const int* __restrict__ src, const int* __restrict__ dst, int* __restrict__ cursor,
    const float* __restrict__ u_part, const float* __restrict__ a12,
    const float* __restrict__ b_att,
    int* __restrict__ src_sorted, float* __restrict__ u_sorted, int E)
{
  int e = blockIdx.x * blockDim.x + threadIdx.x;
  if (e >= E) return;
  int dN = dst[e], sN = src[e];
  int p = atomicAdd(&cursor[dN], 1);
  src_sorted[p] = sN;
  float4 up = *reinterpret_cast<const float4*>(&u_part[(long long)e * 4]);
  float4 a1 = *reinterpret_cast<const float4*>(&a12[(long long)dN * 8]);
  float4 a2 = *reinterpret_cast<const float4*>(&a12[(long long)sN * 8 + 4]);
  float4 ba = *reinterpret_cast<const float4*>(&b_att[0]);
  float4 o;
  o.x = a1.x + a2.x + up.x + ba.x; o.x = (o.x >= 0.f) ? o.x : LEAKY * o.x;
  o.y = a1.y + a2.y + up.y + ba.y; o.y = (o.y >= 0.f) ? o.y : LEAKY * o.y;
  o.z = a1.z + a2.z + up.z + ba.z; o.z = (o.z >= 0.f) ? o.z : LEAKY * o.z;
  o.w = a1.w + a2.w + up.w + ba.w; o.w = (o.w >= 0.f) ? o.w : LEAKY * o.w;
  *reinterpret_cast<float4*>(&u_sorted[(long long)p * 4]) = o;
}

// ---------- online segment softmax + gather aggregate (wave per node, 1-deep pipeline) ----------
__global__ __launch_bounds__(256) void node_agg_kernel(
    const float* __restrict__ h, const int* __restrict__ src_sorted,
    const float* __restrict__ u_sorted, const int* __restrict__ row_ptr,
    unsigned short* __restrict__ t, int N)
{
  int lane = threadIdx.x & 63;
  int n = (int)((blockIdx.x * (long long)blockDim.x + threadIdx.x) >> 6);
  if (n >= N) return;
  int lo = row_ptr[n], hi = row_ptr[n + 1];
  unsigned short* tb = &t[(long long)n * 512];
  if (lo == hi) {
#pragma unroll
    for (int hd = 0; hd < 4; ++hd) {
      tb[hd * 128 + lane] = 0;
      tb[hd * 128 + 64 + lane] = 0;
    }
    return;
  }
  float m0 = -1e30f, m1 = -1e30f, m2 = -1e30f, m3 = -1e30f;
  float d0 = 0.f, d1 = 0.f, d2 = 0.f, d3 = 0.f;
  float acc[8];
#pragma unroll
  for (int i = 0; i < 8; ++i) acc[i] = 0.f;

  // prime pipeline
  int sN = src_sorted[lo];
  float4 u = *reinterpret_cast<const float4*>(&u_sorted[(long long)lo * 4]);
  const float* hs = &h[(long long)sN * D_DIM];
  float h0 = hs[lane], h1 = hs[64 + lane];

  for (int p = lo; p < hi; ++p) {
    float4 uc = u;
    float h0c = h0, h1c = h1;
    if (p + 1 < hi) {             // prefetch next edge while computing current
      int sn2 = src_sorted[p + 1];
      u = *reinterpret_cast<const float4*>(&u_sorted[(long long)(p + 1) * 4]);
      const float* hs2 = &h[(long long)sn2 * D_DIM];
      h0 = hs2[lane]; h1 = hs2[64 + lane];
    }
    float nm0 = fmaxf(m0, uc.x), nm1 = fmaxf(m1, uc.y);
    float nm2 = fmaxf(m2, uc.z), nm3 = fmaxf(m3, uc.w);
    float s0 = __expf(m0 - nm0), s1 = __expf(m1 - nm1);
    float s2 = __expf(m2 - nm2), s3 = __expf(m3 - nm3);
    float p0 = __expf(uc.x - nm0), p1 = __expf(uc.y - nm1);
    float p2 = __expf(uc.z - nm2), p3 = __expf(uc.w - nm3);
    m0 = nm0; m1 = nm1; m2 = nm2; m3 = nm3;
    d0 = fmaf(d0, s0, p0); d1 = fmaf(d1, s1, p1);
    d2 = fmaf(d2, s2, p2); d3 = fmaf(d3, s3, p3);
    acc[0] = fmaf(acc[0], s0, p0 * h0c); acc[1] = fmaf(acc[1], s0, p0 * h1c);
    acc[2] = fmaf(acc[2], s1, p1 * h0c); acc[3] = fmaf(acc[3], s1, p1 * h1c);
    acc[4] = fmaf(acc[4], s2, p2 * h0c); acc[5] = fmaf(acc[5], s2, p2 * h1c);
    acc[6] = fmaf(acc[6], s3, p3 * h0c); acc[7] = fmaf(acc[7], s3, p3 * h1c);
  }
  float r0 = 1.f / d0, r1 = 1.f / d1, r2 = 1.f / d2, r3 = 1.f / d3;
  tb[0 * 128 + lane] = f2bf(acc[0] * r0); tb[0 * 128 + 64 + lane] = f2bf(acc[1] * r0);
  tb[1 * 128 + lane] = f2bf(acc[2] * r1); tb[1 * 128 + 64 + lane] = f2bf(acc[3] * r1);
  tb[2 * 128 + lane] = f2bf(acc[4] * r2); tb[2 * 128 + 64 + lane] = f2bf(acc[5] * r2);
  tb[3 * 128 + lane] = f2bf(acc[6] * r3); tb[3 * 128 + 64 + lane] = f2bf(acc[7] * r3);
}

// ---------- final node GEMM via MFMA ----------
__global__ __launch_bounds__(256) void node_final_mfma(
    const unsigned short* __restrict__ t_bf, const unsigned short* __restrict__ ww_pk,
    const float* __restrict__ b_w, const int* __restrict__ row_ptr,
    const float* __restrict__ h, const float* __restrict__ prelu_a,
    float* __restrict__ out, int N)
{
  int l = threadIdx.x & 63;
  int wv = threadIdx.x >> 6;
  int base = blockIdx.x * 128 + wv * 32;

  f32x4 zero4 = {0.f, 0.f, 0.f, 0.f};
  f32x4 acc[2][8];
#pragma unroll
  for (int rg = 0; rg < 2; ++rg)
#pragma unroll
    for (int dg = 0; dg < 8; ++dg) acc[rg][dg] = zero4;

  s16x8 azero;
#pragma unroll
  for (int j = 0; j < 8; ++j) azero[j] = 0;

  for (int kc = 0; kc < 16; ++kc) {
    s16x8 a[2];
#pragma unroll
    for (int rg = 0; rg < 2; ++rg) {
      int row = base + rg * 16 + (l & 15);
      a[rg] = (row < N)
        ? *reinterpret_cast<const s16x8*>(&t_bf[(long long)row * 512 + kc * 32 + 8 * (l >> 4)])
        : azero;
    }
#pragma unroll
    for (int dg = 0; dg < 8; ++dg) {
      s16x8 b = *reinterpret_cast<const s16x8*>(&ww_pk[((long long)(kc * 8 + dg) * 64 + l) * 8]);
      acc[0][dg] = __builtin_amdgcn_mfma_f32_16x16x32_bf16(a[0], b, acc[0][dg], 0, 0, 0);
      acc[1][dg] = __builtin_amdgcn_mfma_f32_16x16x32_bf16(a[1], b, acc[1][dg], 0, 0, 0);
    }
  }

  float pa = prelu_a[0];
  int cq = l & 15;
  float bs[8];
#pragma unroll
  for (int dg = 0; dg < 8; ++dg) {
    int col = 16 * dg + cq;
    bs[dg] = b_w[col] + b_w[128 + col] + b_w[256 + col] + b_w[384 + col];
  }
#pragma unroll
  for (int rg = 0; rg < 2; ++rg)
#pragma unroll
    for (int i = 0; i < 4; ++i) {
      int row = base + rg * 16 + 4 * (l >> 4) + i;
      if (row >= N) continue;
      bool has = row_ptr[row + 1] > row_ptr[row];
#pragma unroll
      for (int dg = 0; dg < 8; ++dg) {
        int col = 16 * dg + cq;
        float v = (acc[rg][dg][i] + bs[dg]) * 0.25f;
        v = (v >= 0.f) ? v : pa * v;
        if (!has) v = h[(long long)row * 128 + col];
        out[(long long)row * 128 + col] = v;
      }
    }
}

extern "C" void kernel_launch(void* const* d_in, const int* in_sizes, int n_in,
                              void* d_out, int out_size, void* d_ws, size_t ws_size,
                              hipStream_t stream)
{
  const float* h         = (const float*)d_in[0];
  const float* edge_feat = (const float*)d_in[1];
  const int*   src       = (const int*)d_in[2];
  const int*   dst       = (const int*)d_in[3];
  const float* W_rel     = (const float*)d_in[4];
  const float* b_rel     = (const float*)d_in[5];
  const float* ln_g      = (const float*)d_in[6];
  const float* ln_b      = (const float*)d_in[7];
  const float* W_att     = (const float*)d_in[8];
  const float* b_att     = (const float*)d_in[9];
  const float* W_w       = (const float*)d_in[10];
  const float* b_w       = (const float*)d_in[11];
  const float* prelu_a   = (const float*)d_in[12];

  int N = in_sizes[0] / D_DIM;
  int E = in_sizes[2];
  int nb = (N + 1023) / 1024;

  char* ws = (char*)d_ws;
  size_t off = 0;
  unsigned short* t_bf    = (unsigned short*)(ws + off); off += (size_t)N * 512 * 2;
  float* u_part           = (float*)(ws + off);          off += (size_t)E * 4 * 4;
  float* u_sorted         = (float*)(ws + off);          off += (size_t)E * 4 * 4;
  float* a12              = (float*)(ws + off);          off += (size_t)N * 8 * 4;
  int*   row_ptr          = (int*)(ws + off);            off += (size_t)(N + 1) * 4;
  int*   cnt              = (int*)(ws + off);            off += (size_t)N * 4;
  int*   cursor           = (int*)(ws + off);            off += (size_t)N * 4;
  int*   src_sorted       = (int*)(ws + off);            off += (size_t)E * 4;
  unsigned short* wrel_pk = (unsigned short*)(ws + off); off += 8192 * 2;
  unsigned short* ww_pk   = (unsigned short*)(ws + off); off += 65536 * 2;
  int*   bsum             = (int*)(ws + off);            off += 64 * 4;
  int*   boff             = (int*)(ws + off);            off += 64 * 4;

  hipMemsetAsync(cnt, 0, (size_t)N * 4, stream);
  hist_kernel<<<(E + 255) / 256, 256, 0, stream>>>(dst, cnt, E);
  scan1_kernel<<<nb, 256, 0, stream>>>(cnt, bsum, N);
  scan2_kernel<<<1, 64, 0, stream>>>(bsum, boff, &row_ptr[N], nb);
  scan3_kernel<<<nb, 256, 0, stream>>>(cnt, boff, row_ptr, cursor, N);
  prep_weights_kernel<<<288, 256, 0, stream>>>(W_rel, W_w, wrel_pk, ww_pk);
  node_att_kernel<<<(N * 64 + 255) / 256, 256, 0, stream>>>(h, W_att, a12, N);
  edge_mfma_kernel<<<(E + 63) / 64, 256, 0, stream>>>(edge_feat, wrel_pk, b_rel,
                                                      ln_g, ln_b, W_att, u_part, E);
  scatter_logit_kernel<<<(E + 255) / 256, 256, 0, stream>>>(src, dst, cursor, u_part, a12,
                                                            b_att, src_sorted, u_sorted, E);
  node_agg_kernel<<<(int)(((long long)N * 64 + 255) / 256), 256, 0, stream>>>(
      h, src_sorted, u_sorted, row_ptr, t_bf, N);
  node_final_mfma<<<(N + 127) / 128, 256, 0, stream>>>(t_bf, ww_pk, b_w, row_ptr, h, prelu_a,
                                                       (float*)d_out, N);
}